// Round 12
// baseline (273.215 us; speedup 1.0000x reference)
//
#include <hip/hip_runtime.h>
#include <hip/hip_bf16.h>
#include <stdint.h>

// Problem constants (AudioEncoder_14800457302115)
// R12 = R11 (best, 256.8 us) + natural-VGPR diet for 3 waves/SIMD occupancy:
//   f16-packed conv weights+bias (R6-verified numerics), bias at store-read,
//   GRID 768 (3 blk/CU residency). NO launch_bounds (R3/R6/R8: it spills).
#define B_SZ    4
#define T_LEN   480000
#define S_LEN   240000          // (480000 + 2*2 - 5)/2 + 1
#define KS      5
#define PPB     7500            // 32-s tile-PAIRS per batch (240000/32)
#define NPAIRS  (B_SZ * PPB)    // 30000 wave-pairs
#define GRID    768             // 3 blocks/CU x 256 CU (resident iff VGPR<=170)

static_assert(4 * GRID <= PPB, "single-wrap batch advance requires nw <= PPB");

typedef __attribute__((ext_vector_type(8))) __bf16    bf16x8;
typedef __attribute__((ext_vector_type(4))) float     f32x4;
typedef __attribute__((ext_vector_type(2))) _Float16  f16x2;

__global__ __launch_bounds__(256) void audio_enc_kernel(
    const float* __restrict__ audio,   // (B, T)
    const float* __restrict__ conv_w,  // (64, 1, 5)
    const float* __restrict__ conv_b,  // (64,)
    const float* __restrict__ lin_w,   // (64, 64) [p][e]
    const float* __restrict__ lin_b,   // (64,)
    float* __restrict__ out)           // (B, S, 64)
{
  const int lane = threadIdx.x & 63;
  const int m    = lane & 15;          // fragment free index (p for A, s for B)
  const int q    = lane >> 4;          // quad
  const int wid  = threadIdx.x >> 6;   // wave within block
  const int wv   = (int)((blockIdx.x << 2) | wid);
  const int nw   = (int)(gridDim.x << 2);

  // per-wave 8 KB staging (two 16-s tiles) for the store-layout transpose
  __shared__ float lds[4][2048];
  float* const lw = lds[wid];

  // ---- one-time, tile-invariant register state (VGPR diet) ----
  // conv weights packed f16 (48 VGPR vs 80 fp32; R6-verified: absmax unchanged)
  // conv bias packed f16 pairs (8 VGPR vs 16; bias ~0.01 scale, f16 rounding
  // ~1e-5 abs << bf16 MFMA error)
  f16x2 cwp[2][8][3];
  f16x2 cbp[2][4];
#pragma unroll
  for (int h = 0; h < 2; ++h) {
#pragma unroll
    for (int j = 0; j < 8; ++j) {
      const int e = h * 32 + q * 8 + j;
      const float* w = conv_w + e * KS;
      cwp[h][j][0] = f16x2{(_Float16)w[0], (_Float16)w[1]};
      cwp[h][j][1] = f16x2{(_Float16)w[2], (_Float16)w[3]};
      cwp[h][j][2] = f16x2{(_Float16)w[4], (_Float16)0.f};
    }
#pragma unroll
    for (int jj = 0; jj < 4; ++jj) {
      const int e = h * 32 + q * 8 + jj * 2;
      cbp[h][jj] = f16x2{(_Float16)conv_b[e], (_Float16)conv_b[e + 1]};
    }
  }

  // lin_w as the MFMA *A* operand:
  // A[p][e]; lane: row = m -> p = nt*16+m, k = q*8+j -> e = kt*32+q*8+j
  bf16x8 wfrag[2][4];
#pragma unroll
  for (int nt = 0; nt < 4; ++nt) {
    const int p = nt * 16 + m;
#pragma unroll
    for (int kt = 0; kt < 2; ++kt) {
      const float* src = lin_w + p * 64 + kt * 32 + q * 8;
#pragma unroll
      for (int j = 0; j < 8; ++j) wfrag[kt][nt][j] = (__bf16)src[j];
    }
  }

  // lin_b in STORE lane layout (4 VGPR, replaces 16-reg lb4):
  // store lane l elem k covers out column p = (l&15)*4 + k
  const f32x4 bias4 = *reinterpret_cast<const f32x4*>(lin_b + m * 4);

  if (wv >= NPAIRS) return;
  int b0 = wv / PPB;                   // current pair id (b0, sp0)
  int sp0 = wv - b0 * PPB;
  int sp1 = sp0 + nw, b1 = b0;         // next pair id
  if (sp1 >= PPB) { sp1 -= PPB; ++b1; }
  bool v1 = (b1 < B_SZ);

  // ---- 16-s tile window loader (branchless edge clamp) ----
  auto load_tile = [&](int bb, int s0, float2& A, float2& Bv, float& C) {
    const float* base = audio + (size_t)bb * T_LEN;
    const int sl = s0 + m;
    const int gi = 2 * sl - 2;                    // window start (pad=2)
    A = *reinterpret_cast<const float2*>(base + (gi < 0 ? 0 : gi));
    if (gi < 0) { A.x = 0.f; A.y = 0.f; }         // only s==0, m==0
    Bv = *reinterpret_cast<const float2*>(base + 2 * sl);
    const int ci = 2 * sl + 2;
    const float cv = base[ci < T_LEN ? ci : T_LEN - 1];
    C = (ci < T_LEN) ? cv : 0.f;                  // only sl==239999
  };

  // ---- compute + store for one pair ----
  auto body = [&](const float* xs0, const float* xs1, int bc, int s0c) {
    // conv -> feature fragments for both tiles (weights amortized)
    bf16x8 xf0[2], xf1[2];
#pragma unroll
    for (int h = 0; h < 2; ++h)
#pragma unroll
      for (int j = 0; j < 8; ++j) {
        const float w0 = (float)cwp[h][j][0][0];
        const float w1 = (float)cwp[h][j][0][1];
        const float w2 = (float)cwp[h][j][1][0];
        const float w3 = (float)cwp[h][j][1][1];
        const float w4 = (float)cwp[h][j][2][0];
        const float bb = (float)cbp[h][j >> 1][j & 1];
        float a0 = bb, a1 = bb;
        a0 = fmaf(w0, xs0[0], a0);  a1 = fmaf(w0, xs1[0], a1);
        a0 = fmaf(w1, xs0[1], a0);  a1 = fmaf(w1, xs1[1], a1);
        a0 = fmaf(w2, xs0[2], a0);  a1 = fmaf(w2, xs1[2], a1);
        a0 = fmaf(w3, xs0[3], a0);  a1 = fmaf(w3, xs1[3], a1);
        a0 = fmaf(w4, xs0[4], a0);  a1 = fmaf(w4, xs1[4], a1);
        xf0[h][j] = (__bf16)fmaxf(a0, 0.f);
        xf1[h][j] = (__bf16)fmaxf(a1, 0.f);
      }

    // MFMA both tiles; stage to LDS (XOR-swizzled, conflict-free)
    // D layout: row(p-in-chunk) = q*4+r, col(s) = m
#pragma unroll
    for (int nt = 0; nt < 4; ++nt) {
      f32x4 acc0 = {0.f, 0.f, 0.f, 0.f};
      acc0 = __builtin_amdgcn_mfma_f32_16x16x32_bf16(wfrag[0][nt], xf0[0], acc0, 0, 0, 0);
      acc0 = __builtin_amdgcn_mfma_f32_16x16x32_bf16(wfrag[1][nt], xf0[1], acc0, 0, 0, 0);
      *reinterpret_cast<f32x4*>(lw + m * 64 + ((nt * 16 + q * 4) ^ (m << 2))) = acc0;
      f32x4 acc1 = {0.f, 0.f, 0.f, 0.f};
      acc1 = __builtin_amdgcn_mfma_f32_16x16x32_bf16(wfrag[0][nt], xf1[0], acc1, 0, 0, 0);
      acc1 = __builtin_amdgcn_mfma_f32_16x16x32_bf16(wfrag[1][nt], xf1[1], acc1, 0, 0, 0);
      *reinterpret_cast<f32x4*>(lw + 1024 + m * 64 + ((nt * 16 + q * 4) ^ (m << 2))) = acc1;
    }

    // read back in store order; 8 x 1024 B contiguous stores; bias here
    // read lane l, instr g: tile u = g>>2, r = (g&3)*4 + (l>>4),
    //   word = u*1024 + r*64 + (((l&15)<<2) ^ (r<<2))
    float* ob = out + ((size_t)bc * S_LEN + (size_t)s0c) * 64;
#pragma unroll
    for (int g = 0; g < 8; ++g) {
      const int r = (g & 3) * 4 + q;
      f32x4 v = *reinterpret_cast<const f32x4*>(
          lw + (g >> 2) * 1024 + r * 64 + ((m << 2) ^ (r << 2)));
      v = v + bias4;
      *reinterpret_cast<f32x4*>(ob + g * 256 + lane * 4) = v;
    }
  };

  // ---- prefetch depth 2: two named pair-buffers, 2-phase ping-pong ----
  float2 A0a, B0a, A0b, B0b; float C0a, C0b;   // buffer P0
  float2 A1a, B1a, A1b, B1b; float C1a, C1b;   // buffer P1

  load_tile(b0, sp0 * 32,      A0a, B0a, C0a);
  load_tile(b0, sp0 * 32 + 16, A0b, B0b, C0b);
  if (v1) {
    load_tile(b1, sp1 * 32,      A1a, B1a, C1a);
    load_tile(b1, sp1 * 32 + 16, A1b, B1b, C1b);
  }

  while (true) {
    // ---- phase A: current in P0, next in P1; prefetch (cur+2) -> P0 ----
    {
      const float xs0[KS] = {A0a.x, A0a.y, B0a.x, B0a.y, C0a};
      const float xs1[KS] = {A0b.x, A0b.y, B0b.x, B0b.y, C0b};
      int sp2 = sp1 + nw, b2 = b1;
      if (sp2 >= PPB) { sp2 -= PPB; ++b2; }
      const bool v2 = (b2 < B_SZ);
      if (v2) {                                  // in flight for 2 iterations
        load_tile(b2, sp2 * 32,      A0a, B0a, C0a);
        load_tile(b2, sp2 * 32 + 16, A0b, B0b, C0b);
      }
      body(xs0, xs1, b0, sp0 * 32);
      if (!v1) break;
      b0 = b1; sp0 = sp1; b1 = b2; sp1 = sp2; v1 = v2;
    }
    // ---- phase B: current in P1, next in P0; prefetch (cur+2) -> P1 ----
    {
      const float xs0[KS] = {A1a.x, A1a.y, B1a.x, B1a.y, C1a};
      const float xs1[KS] = {A1b.x, A1b.y, B1b.x, B1b.y, C1b};
      int sp2 = sp1 + nw, b2 = b1;
      if (sp2 >= PPB) { sp2 -= PPB; ++b2; }
      const bool v2 = (b2 < B_SZ);
      if (v2) {
        load_tile(b2, sp2 * 32,      A1a, B1a, C1a);
        load_tile(b2, sp2 * 32 + 16, A1b, B1b, C1b);
      }
      body(xs0, xs1, b0, sp0 * 32);
      if (!v1) break;
      b0 = b1; sp0 = sp1; b1 = b2; sp1 = sp2; v1 = v2;
    }
  }
}

extern "C" void kernel_launch(void* const* d_in, const int* in_sizes, int n_in,
                              void* d_out, int out_size, void* d_ws, size_t ws_size,
                              hipStream_t stream) {
  const float* audio  = (const float*)d_in[0];
  const float* conv_w = (const float*)d_in[1];
  const float* conv_b = (const float*)d_in[2];
  const float* lin_w  = (const float*)d_in[3];
  const float* lin_b  = (const float*)d_in[4];
  float* out = (float*)d_out;

  audio_enc_kernel<<<dim3(GRID), dim3(256), 0, stream>>>(
      audio, conv_w, conv_b, lin_w, lin_b, out);
}

// Round 13
// 254.953 us; speedup vs baseline: 1.0716x; 1.0716x over previous
//
#include <hip/hip_runtime.h>
#include <hip/hip_bf16.h>
#include <stdint.h>

// Problem constants (AudioEncoder_14800457302115)
// R13 = R11 (best, 256.8 us) + DEFERRED STORE PIPELINE (single variable):
//   pair i's LDS readback + global stores happen at the TOP of iteration i+1,
//   from a double-buffered per-wave staging area. Breaks the per-iteration
//   store->ds_read WAR drain (stores get a full conv+MFMA+stage to retire).
// Reverted from R12: fp32 conv weights, lb4-in-acc bias, GRID 512.
#define B_SZ    4
#define T_LEN   480000
#define S_LEN   240000          // (480000 + 2*2 - 5)/2 + 1
#define KS      5
#define PPB     7500            // 32-s tile-PAIRS per batch (240000/32)
#define NPAIRS  (B_SZ * PPB)    // 30000 wave-pairs
#define GRID    512             // 2048 waves, 2 blk/CU resident (proven best)

static_assert(4 * GRID <= PPB, "single-wrap batch advance requires nw <= PPB");

typedef __attribute__((ext_vector_type(8))) __bf16  bf16x8;
typedef __attribute__((ext_vector_type(4))) float   f32x4;

__global__ __launch_bounds__(256) void audio_enc_kernel(
    const float* __restrict__ audio,   // (B, T)
    const float* __restrict__ conv_w,  // (64, 1, 5)
    const float* __restrict__ conv_b,  // (64,)
    const float* __restrict__ lin_w,   // (64, 64) [p][e]
    const float* __restrict__ lin_b,   // (64,)
    float* __restrict__ out)           // (B, S, 64)
{
  const int lane = threadIdx.x & 63;
  const int m    = lane & 15;          // fragment free index (p for A, s for B)
  const int q    = lane >> 4;          // quad
  const int wid  = threadIdx.x >> 6;   // wave within block
  const int wv   = (int)((blockIdx.x << 2) | wid);
  const int nw   = (int)(gridDim.x << 2);

  // per-wave DOUBLE-buffered 8 KB staging (two pairs in flight)
  __shared__ float lds[4][2][2048];    // 64 KB/block
  float* const lw0 = lds[wid][0];
  float* const lw1 = lds[wid][1];

  // ---- one-time, tile-invariant register state (R11-proven fp32 weights) ----
  float cw[2][8][KS], cbv[2][8];
#pragma unroll
  for (int h = 0; h < 2; ++h)
#pragma unroll
    for (int j = 0; j < 8; ++j) {
      const int e = h * 32 + q * 8 + j;
#pragma unroll
      for (int t = 0; t < KS; ++t) cw[h][j][t] = conv_w[e * KS + t];
      cbv[h][j] = conv_b[e];
    }

  // lin_w as the MFMA *A* operand:
  // A[p][e]; lane: row = m -> p = nt*16+m, k = q*8+j -> e = kt*32+q*8+j
  bf16x8 wfrag[2][4];
#pragma unroll
  for (int nt = 0; nt < 4; ++nt) {
    const int p = nt * 16 + m;
#pragma unroll
    for (int kt = 0; kt < 2; ++kt) {
      const float* src = lin_w + p * 64 + kt * 32 + q * 8;
#pragma unroll
      for (int j = 0; j < 8; ++j) wfrag[kt][nt][j] = (__bf16)src[j];
    }
  }

  // lin_b folded into accumulator init: acc[r] is output column p = nt*16+q*4+r
  f32x4 lb4[4];
#pragma unroll
  for (int nt = 0; nt < 4; ++nt)
    lb4[nt] = *reinterpret_cast<const f32x4*>(lin_b + nt * 16 + q * 4);

  if (wv >= NPAIRS) return;
  int b0 = wv / PPB;                   // current pair id (b0, sp0)
  int sp0 = wv - b0 * PPB;
  int sp1 = sp0 + nw, b1 = b0;         // next pair id
  if (sp1 >= PPB) { sp1 -= PPB; ++b1; }
  bool v1 = (b1 < B_SZ);

  // ---- 16-s tile window loader (branchless edge clamp) ----
  auto load_tile = [&](int bb, int s0, float2& A, float2& Bv, float& C) {
    const float* base = audio + (size_t)bb * T_LEN;
    const int sl = s0 + m;
    const int gi = 2 * sl - 2;                    // window start (pad=2)
    A = *reinterpret_cast<const float2*>(base + (gi < 0 ? 0 : gi));
    if (gi < 0) { A.x = 0.f; A.y = 0.f; }         // only s==0, m==0
    Bv = *reinterpret_cast<const float2*>(base + 2 * sl);
    const int ci = 2 * sl + 2;
    const float cv = base[ci < T_LEN ? ci : T_LEN - 1];
    C = (ci < T_LEN) ? cv : 0.f;                  // only sl==239999
  };

  // ---- conv + MFMA + stage one pair into LDS buffer ----
  auto stage = [&](float* buf, const float* xs0, const float* xs1) {
    bf16x8 xf0[2], xf1[2];
#pragma unroll
    for (int h = 0; h < 2; ++h)
#pragma unroll
      for (int j = 0; j < 8; ++j) {
        float a0 = cbv[h][j], a1 = cbv[h][j];
#pragma unroll
        for (int t = 0; t < KS; ++t) {
          a0 = fmaf(cw[h][j][t], xs0[t], a0);
          a1 = fmaf(cw[h][j][t], xs1[t], a1);
        }
        xf0[h][j] = (__bf16)fmaxf(a0, 0.f);
        xf1[h][j] = (__bf16)fmaxf(a1, 0.f);
      }
    // D layout: row(p-in-chunk) = q*4+r, col(s) = m; XOR-swizzled stage
#pragma unroll
    for (int nt = 0; nt < 4; ++nt) {
      f32x4 acc0 = lb4[nt];
      acc0 = __builtin_amdgcn_mfma_f32_16x16x32_bf16(wfrag[0][nt], xf0[0], acc0, 0, 0, 0);
      acc0 = __builtin_amdgcn_mfma_f32_16x16x32_bf16(wfrag[1][nt], xf0[1], acc0, 0, 0, 0);
      *reinterpret_cast<f32x4*>(buf + m * 64 + ((nt * 16 + q * 4) ^ (m << 2))) = acc0;
      f32x4 acc1 = lb4[nt];
      acc1 = __builtin_amdgcn_mfma_f32_16x16x32_bf16(wfrag[0][nt], xf1[0], acc1, 0, 0, 0);
      acc1 = __builtin_amdgcn_mfma_f32_16x16x32_bf16(wfrag[1][nt], xf1[1], acc1, 0, 0, 0);
      *reinterpret_cast<f32x4*>(buf + 1024 + m * 64 + ((nt * 16 + q * 4) ^ (m << 2))) = acc1;
    }
  };

  // ---- readback previously-staged pair + 8 x 1024 B contiguous stores ----
  // read lane l, instr g: tile u = g>>2, r = (g&3)*4 + (l>>4),
  //   word = u*1024 + r*64 + (((l&15)<<2) ^ (r<<2))
  auto drain = [&](const float* buf, int bc, int s0c) {
    float* ob = out + ((size_t)bc * S_LEN + (size_t)s0c) * 64;
#pragma unroll
    for (int g = 0; g < 8; ++g) {
      const int r = (g & 3) * 4 + q;
      const f32x4 v = *reinterpret_cast<const f32x4*>(
          buf + (g >> 2) * 1024 + r * 64 + ((m << 2) ^ (r << 2)));
      *reinterpret_cast<f32x4*>(ob + g * 256 + lane * 4) = v;
    }
  };

  // ---- prefetch depth 2 (R11): two named pair-buffers, 2-phase ping-pong ----
  float2 A0a, B0a, A0b, B0b; float C0a, C0b;   // buffer P0
  float2 A1a, B1a, A1b, B1b; float C1a, C1b;   // buffer P1

  load_tile(b0, sp0 * 32,      A0a, B0a, C0a);
  load_tile(b0, sp0 * 32 + 16, A0b, B0b, C0b);
  if (v1) {
    load_tile(b1, sp1 * 32,      A1a, B1a, C1a);
    load_tile(b1, sp1 * 32 + 16, A1b, B1b, C1b);
  }

  // deferred-drain state: pair staged last phase, not yet stored
  bool pend = false; int pb = 0, ps0 = 0;
  const float* pbuf = lw0;

  while (true) {
    // ---- phase A: current in P0, stage into lw0; drain previous (lw1) ----
    {
      const float xs0[KS] = {A0a.x, A0a.y, B0a.x, B0a.y, C0a};
      const float xs1[KS] = {A0b.x, A0b.y, B0b.x, B0b.y, C0b};
      int sp2 = sp1 + nw, b2 = b1;
      if (sp2 >= PPB) { sp2 -= PPB; ++b2; }
      const bool v2 = (b2 < B_SZ);
      if (v2) {                                  // in flight for 2 iterations
        load_tile(b2, sp2 * 32,      A0a, B0a, C0a);
        load_tile(b2, sp2 * 32 + 16, A0b, B0b, C0b);
      }
      if (pend) drain(pbuf, pb, ps0);            // stores of pair i-1
      stage(lw0, xs0, xs1);                      // compute pair i
      pend = true; pbuf = lw0; pb = b0; ps0 = sp0 * 32;
      if (!v1) break;
      b0 = b1; sp0 = sp1; b1 = b2; sp1 = sp2; v1 = v2;
    }
    // ---- phase B: current in P1, stage into lw1; drain previous (lw0) ----
    {
      const float xs0[KS] = {A1a.x, A1a.y, B1a.x, B1a.y, C1a};
      const float xs1[KS] = {A1b.x, A1b.y, B1b.x, B1b.y, C1b};
      int sp2 = sp1 + nw, b2 = b1;
      if (sp2 >= PPB) { sp2 -= PPB; ++b2; }
      const bool v2 = (b2 < B_SZ);
      if (v2) {
        load_tile(b2, sp2 * 32,      A1a, B1a, C1a);
        load_tile(b2, sp2 * 32 + 16, A1b, B1b, C1b);
      }
      drain(pbuf, pb, ps0);                      // pend is always true here
      stage(lw1, xs0, xs1);
      pbuf = lw1; pb = b0; ps0 = sp0 * 32;
      if (!v1) break;
      b0 = b1; sp0 = sp1; b1 = b2; sp1 = sp2; v1 = v2;
    }
  }

  // epilogue: store the last staged pair
  drain(pbuf, pb, ps0);
}

extern "C" void kernel_launch(void* const* d_in, const int* in_sizes, int n_in,
                              void* d_out, int out_size, void* d_ws, size_t ws_size,
                              hipStream_t stream) {
  const float* audio  = (const float*)d_in[0];
  const float* conv_w = (const float*)d_in[1];
  const float* conv_b = (const float*)d_in[2];
  const float* lin_w  = (const float*)d_in[3];
  const float* lin_b  = (const float*)d_in[4];
  float* out = (float*)d_out;

  audio_enc_kernel<<<dim3(GRID), dim3(256), 0, stream>>>(
      audio, conv_w, conv_b, lin_w, lin_b, out);
}